// Round 13
// baseline (102.788 us; speedup 1.0000x reference)
//
#include <hip/hip_runtime.h>

// Problem dims
#define BN 8
#define BC 128
#define BH 56
#define BW 56
#define HW 3136
#define NTAP 35
// u16 offsets inside ws:
#define WS_WC 71680                   // stage-2 Wc fragments [WS_WC, WS_WC+4096)
#define WS_XP (WS_WC + 4096)          // padded bf16 im2row x
#define XROW 2368                     // u16 per padded row = 74 cols * 32 ch

typedef unsigned short u16;
typedef unsigned int u32;
typedef __bf16 bf16x8 __attribute__((ext_vector_type(8)));
typedef float f32x4 __attribute__((ext_vector_type(4)));

__device__ __forceinline__ u16 f2b(float f) {
    unsigned u = __float_as_uint(f);
    return (u16)((u + 0x7FFFu + ((u >> 16) & 1u)) >> 16);  // RNE
}
__device__ __forceinline__ u32 pack2(float a, float b) {
    return (u32)f2b(a) | ((u32)f2b(b) << 16);
}
__device__ __forceinline__ void dma16(const void* g, void* l) {
    __builtin_amdgcn_global_load_lds(
        (const __attribute__((address_space(1))) u32*)g,
        (__attribute__((address_space(3))) u32*)l, 16, 0, 0);
}

// prep_all: blocks [0,2048) build padded bf16 im2row x; blocks [2048,2344)
// build frag-ordered w3 + folded Wc (= w5@w4, K zero-padded to 32).
__global__ __launch_bounds__(256) void prep_all(
    const float* __restrict__ x, const float* __restrict__ w3,
    const float* __restrict__ w4, const float* __restrict__ w5,
    u16* __restrict__ ws)
{
    const int b = blockIdx.x;
    const int tid = threadIdx.x;

    if (b >= 2048) {               // ---- weights part
        int i = (b - 2048) * 256 + tid;
        if (i < WS_WC) {
            int j = i & 7, lane = (i >> 3) & 63, r = i >> 9;   // r = cc*35+tap
            int tap = r % NTAP, cc = r / NTAP;
            int q = lane >> 4, lm = lane & 15;
            ws[i] = f2b(w3[(lm * BC + cc * 32 + q * 8 + j) * NTAP + tap]);
        } else if (i < WS_WC + 4096) {
            int i2 = i - WS_WC;
            int j = i2 & 7, lane = (i2 >> 3) & 63, ot = i2 >> 9;
            int q = lane >> 4, lm = lane & 15, o = ot * 16 + lm, k = q * 8 + j;
            float s = 0.f;
            if (k < 16)
                for (int c = 0; c < 16; ++c) s += w5[o * 16 + c] * w4[c * 16 + k];
            ws[i] = f2b(s);
        }
        return;
    }

    // ---- x part: xpad[n][cc][hp][col][c32] bf16, h/w zero-pad baked in.
    __shared__ float ls[32][57];
    const int hp = b & 63, cc = (b >> 6) & 3, n = b >> 8;
    u32* dst = (u32*)(ws + WS_XP + (size_t)((n * 4 + cc) * 64 + hp) * XROW);
    const int gr = hp - 4;

    if ((unsigned)gr >= BH) {
        for (int i = tid; i < XROW / 2; i += 256) dst[i] = 0u;
        return;
    }
    for (int i = tid; i < 32 * 14; i += 256) {
        int c = i / 14, w4i = i % 14;
        float4 v = *(const float4*)(x + ((size_t)(n * BC + cc * 32 + c) * BH + gr) * BW + 4 * w4i);
        ls[c][4 * w4i + 0] = v.x;
        ls[c][4 * w4i + 1] = v.y;
        ls[c][4 * w4i + 2] = v.z;
        ls[c][4 * w4i + 3] = v.w;
    }
    __syncthreads();
    for (int i = tid; i < 74 * 16; i += 256) {
        int col = i >> 4, cp = i & 15;
        int gw = col - 9;
        u32 v = 0u;
        if ((unsigned)gw < BW) v = pack2(ls[2 * cp][gw], ls[2 * cp + 1][gw]);
        dst[col * 16 + cp] = v;
    }
}

// Main: block=(n,h), 512 threads = 8 waves. K-split: wave-group 0 (waves 0-3)
// taps 0..17, group 1 (waves 4-7) taps 18..34; fp32 combine via LDS.
// Stage-2: group g does o-tiles 4g..4g+3, each wave over its OWN col-slice
// (full 8x4 coverage). ALL fragment loads + MFMAs unconditional (full exec);
// only stores are guarded -- divergent-exec MFMA with unloaded A-frags was
// R12's NaN source.
__global__ __launch_bounds__(512, 4) void conv_mfma(
    const u16* __restrict__ wsT, float* __restrict__ out)
{
    __shared__ __align__(16) u16 xs[5][74][32];    // 23,680 B (DMA region)
    __shared__ __align__(16) u16 wA[NTAP][64][8];  // 35,840 B (DMA region)
    __shared__ __align__(16) u16 y3T[64][40];      //  5,120 B
    __shared__ float cbuf[4][64][5];               //  5,120 B (pad 5: conflict-free)
    // total 69,760 B -> 2 blocks/CU -> 16 waves/CU

    const int n = blockIdx.x & 7, h = blockIdx.x >> 3;
    const int tid = threadIdx.x, lane = tid & 63, wv = tid >> 6;
    const int wgrp = wv >> 2, wvl = wv & 3;
    const int q = lane >> 4, lm = lane & 15, wpos = wvl * 16 + lm;
    const bool wok = (wpos < BW);

    // one-time: zero y3T k=16..31 (stage-2 K padding); 512 writes, 1/thread
    ((u32*)&y3T[tid >> 3][16])[tid & 7] = 0u;

    f32x4 acc = {0.f, 0.f, 0.f, 0.f};
    char* xsf = (char*)&xs[0][0][0];
    char* wAf = (char*)&wA[0][0][0];
    const int t0 = wgrp ? 18 : 0, t1 = wgrp ? NTAP : 18;

    for (int cc = 0; cc < 4; ++cc) {
        __syncthreads();   // prior cc's frag reads complete

        // xs: 24 chunks of 1 KB DMA (last: 128 B / 8 lanes)
        const u16* xbase = wsT + WS_XP + (size_t)((n * 4 + cc) * 64 + h) * XROW;
        for (int k = wv; k < 24; k += 8) {
            int bb = k * 1024 + lane * 16;
            int r = bb / 4736;               // xs row; global row h+2r pre-padded
            int off = bb - r * 4736;
            if (k < 23 || lane < 8)
                dma16(xbase + (size_t)(2 * r) * XROW + (off >> 1), xsf + bb);
        }
        // wA: 35 chunks of 1 KB, frag-ordered straight copy
        const u16* wbase = wsT + (size_t)cc * NTAP * 512;
        for (int k = wv; k < NTAP; k += 8)
            dma16(wbase + (size_t)k * 512 + lane * 8, wAf + k * 1024 + lane * 16);

        __syncthreads();   // DMA drained + visible

        for (int t = t0; t < t1; ++t) {
            const int kh = t / 7, kw = t % 7;
            bf16x8 a = *(const bf16x8*)&wA[t][lane][0];
            bf16x8 b = *(const bf16x8*)&xs[kh][wpos + 3 * kw][q * 8];
            acc = __builtin_amdgcn_mfma_f32_16x16x32_bf16(a, b, acc, 0, 0, 0);
        }
    }

    // K-split combine: group 1 exports fp32, group 0 adds and writes y3T bf16.
    if (wgrp == 1) {
        cbuf[wvl][lane][0] = acc[0];
        cbuf[wvl][lane][1] = acc[1];
        cbuf[wvl][lane][2] = acc[2];
        cbuf[wvl][lane][3] = acc[3];
    }
    __syncthreads();
    if (wgrp == 0) {
        acc[0] += cbuf[wvl][lane][0];
        acc[1] += cbuf[wvl][lane][1];
        acc[2] += cbuf[wvl][lane][2];
        acc[3] += cbuf[wvl][lane][3];
        // rows >=56 forced to zero (finite) -- their D-columns are discarded
        u32 lo = wok ? pack2(acc[0], acc[1]) : 0u;
        u32 hi = wok ? pack2(acc[2], acc[3]) : 0u;
        *(u32*)&y3T[wpos][q * 4]     = lo;
        *(u32*)&y3T[wpos][q * 4 + 2] = hi;
    }
    __syncthreads();

    // Stage-2: group g -> o-tiles 4g..4g+3 over this wave's col-slice.
    // Frag loads + MFMA unconditional; stores guarded.
    bf16x8 bfrag = *(const bf16x8*)&y3T[wpos][q * 8];
    const int ot0 = wgrp * 4;
    #pragma unroll
    for (int i = 0; i < 4; ++i) {
        const int ot = ot0 + i;
        bf16x8 afrag = *(const bf16x8*)(wsT + WS_WC + (size_t)(ot * 64 + lane) * 8);
        f32x4 c2 = {0.f, 0.f, 0.f, 0.f};
        c2 = __builtin_amdgcn_mfma_f32_16x16x32_bf16(afrag, bfrag, c2, 0, 0, 0);
        if (wok) {
            int o = ot * 16 + q * 4;
            float* po = out + ((size_t)(n * BC + o) * BH + h) * BW + wpos;
            po[0]      = c2[0];
            po[HW]     = c2[1];
            po[2 * HW] = c2[2];
            po[3 * HW] = c2[3];
        }
    }
}

extern "C" void kernel_launch(void* const* d_in, const int* in_sizes, int n_in,
                              void* d_out, int out_size, void* d_ws, size_t ws_size,
                              hipStream_t stream)
{
    (void)in_sizes; (void)n_in; (void)out_size; (void)ws_size;
    const float* x  = (const float*)d_in[0];
    const float* w3 = (const float*)d_in[1];
    const float* w4 = (const float*)d_in[2];
    const float* w5 = (const float*)d_in[3];
    u16* ws = (u16*)d_ws;

    prep_all<<<2048 + 296, 256, 0, stream>>>(x, w3, w4, w5, ws);
    // TIMING PROBE: conv launched TWICE (idempotent; same inputs -> same out).
    // wall = fixed + prep + 2*conv. Decode vs R11 (91.9, conv~27):
    //   wall ~92  -> conv ~13.5 (K-split halved it; drop probe next round)
    //   wall ~119 -> conv ~27   (K-split neutral)
    conv_mfma<<<BN * BH, 512, 0, stream>>>(ws, (float*)d_out);
    conv_mfma<<<BN * BH, 512, 0, stream>>>(ws, (float*)d_out);
}

// Round 14
// 92.357 us; speedup vs baseline: 1.1129x; 1.1129x over previous
//
#include <hip/hip_runtime.h>

// Problem dims
#define BN 8
#define BC 128
#define BH 56
#define BW 56
#define HW 3136
#define NTAP 35
// u16 offsets inside ws:
#define WS_WC 71680                   // stage-2 Wc fragments [WS_WC, WS_WC+4096)
#define WS_XP (WS_WC + 4096)          // padded bf16 im2row x
#define XROW 2368                     // u16 per padded row = 74 cols * 32 ch

typedef unsigned short u16;
typedef unsigned int u32;
typedef __bf16 bf16x8 __attribute__((ext_vector_type(8)));
typedef float f32x4 __attribute__((ext_vector_type(4)));

__device__ __forceinline__ u16 f2b(float f) {
    unsigned u = __float_as_uint(f);
    return (u16)((u + 0x7FFFu + ((u >> 16) & 1u)) >> 16);  // RNE
}
__device__ __forceinline__ u32 pack2(float a, float b) {
    return (u32)f2b(a) | ((u32)f2b(b) << 16);
}
__device__ __forceinline__ void dma16(const void* g, void* l) {
    __builtin_amdgcn_global_load_lds(
        (const __attribute__((address_space(1))) u32*)g,
        (__attribute__((address_space(3))) u32*)l, 16, 0, 0);
}

// prep_all: blocks [0,2048) build padded bf16 im2row x; blocks [2048,2344)
// build frag-ordered w3 + folded Wc (= w5@w4, K zero-padded to 32).
__global__ __launch_bounds__(256) void prep_all(
    const float* __restrict__ x, const float* __restrict__ w3,
    const float* __restrict__ w4, const float* __restrict__ w5,
    u16* __restrict__ ws)
{
    const int b = blockIdx.x;
    const int tid = threadIdx.x;

    if (b >= 2048) {               // ---- weights part
        int i = (b - 2048) * 256 + tid;
        if (i < WS_WC) {
            int j = i & 7, lane = (i >> 3) & 63, r = i >> 9;   // r = cc*35+tap
            int tap = r % NTAP, cc = r / NTAP;
            int q = lane >> 4, lm = lane & 15;
            ws[i] = f2b(w3[(lm * BC + cc * 32 + q * 8 + j) * NTAP + tap]);
        } else if (i < WS_WC + 4096) {
            int i2 = i - WS_WC;
            int j = i2 & 7, lane = (i2 >> 3) & 63, ot = i2 >> 9;
            int q = lane >> 4, lm = lane & 15, o = ot * 16 + lm, k = q * 8 + j;
            float s = 0.f;
            if (k < 16)
                for (int c = 0; c < 16; ++c) s += w5[o * 16 + c] * w4[c * 16 + k];
            ws[i] = f2b(s);
        }
        return;
    }

    // ---- x part: xpad[n][cc][hp][col][c32] bf16, h/w zero-pad baked in.
    __shared__ float ls[32][57];
    const int hp = b & 63, cc = (b >> 6) & 3, n = b >> 8;
    u32* dst = (u32*)(ws + WS_XP + (size_t)((n * 4 + cc) * 64 + hp) * XROW);
    const int gr = hp - 4;

    if ((unsigned)gr >= BH) {
        for (int i = tid; i < XROW / 2; i += 256) dst[i] = 0u;
        return;
    }
    for (int i = tid; i < 32 * 14; i += 256) {
        int c = i / 14, w4i = i % 14;
        float4 v = *(const float4*)(x + ((size_t)(n * BC + cc * 32 + c) * BH + gr) * BW + 4 * w4i);
        ls[c][4 * w4i + 0] = v.x;
        ls[c][4 * w4i + 1] = v.y;
        ls[c][4 * w4i + 2] = v.z;
        ls[c][4 * w4i + 3] = v.w;
    }
    __syncthreads();
    for (int i = tid; i < 74 * 16; i += 256) {
        int col = i >> 4, cp = i & 15;
        int gw = col - 9;
        u32 v = 0u;
        if ((unsigned)gw < BW) v = pack2(ls[2 * cp][gw], ls[2 * cp + 1][gw]);
        dst[col * 16 + cp] = v;
    }
}

// Main: block = (n, h, w-half), 896 blocks x 512 threads (8 waves).
// Wave wv = (wt = wv>>2, g = wv&3): w-tile wt (cols wh*28+wt*16+lm), tap
// quarter g (9/9/9/8). A-frags DIRECT FROM GLOBAL (frag-ordered, batched 9
// outstanding); B-frags from DMA-staged LDS. fp32 K-combine via cbuf, then
// stage-2 (2 o-tiles per wave). MFMA always full-exec; stores guarded.
__global__ __launch_bounds__(512, 4) void conv_mfma(
    const u16* __restrict__ wsT, float* __restrict__ out)
{
    __shared__ __align__(16) u16 xs[5][74][32];    // 23,680 B (DMA region)
    __shared__ __align__(16) u16 y3T[32][40];      //  2,560 B
    __shared__ __align__(16) float cbuf[2][3][64][4]; // 6,144 B
    // total 32,384 B

    const int n = blockIdx.x & 7;
    const int r0 = blockIdx.x >> 3;
    const int h = r0 >> 1, wh = r0 & 1;
    const int tid = threadIdx.x, lane = tid & 63, wv = tid >> 6;
    const int wt = wv >> 2, g = wv & 3;
    const int q = lane >> 4, lm = lane & 15;
    const int wl = wt * 16 + lm;          // local col in half [0,32); valid <28
    const int wg = wh * 28 + wl;          // global col (may exceed 55: guarded)
    const bool wok = (wl < 28);

    // one-time: zero y3T K-pad cols 16..31 (32 rows x 8 u32)
    if (tid < 256) ((u32*)&y3T[tid >> 3][16])[tid & 7] = 0u;

    f32x4 acc = {0.f, 0.f, 0.f, 0.f};
    char* xsf = (char*)&xs[0][0][0];
    const int t0 = 9 * g;
    const int ntap = (g == 3) ? 8 : 9;    // wave-uniform

    for (int cc = 0; cc < 4; ++cc) {
        __syncthreads();   // prior cc's B-reads complete

        // xs: 24 chunks of 1 KB DMA (last: 128 B / 8 lanes), rows h+2r pre-padded
        const u16* xbase = wsT + WS_XP + (size_t)((n * 4 + cc) * 64 + h) * XROW;
        for (int k = wv; k < 24; k += 8) {
            int bb = k * 1024 + lane * 16;
            int r = bb / 4736;
            int off = bb - r * 4736;
            if (k < 23 || lane < 8)
                dma16(xbase + (size_t)(2 * r) * XROW + (off >> 1), xsf + bb);
        }
        __syncthreads();   // DMA drained + visible

        // A-frags: batch-load this wave's 9 taps from global (coalesced 1 KB)
        const u16* wbase = wsT + (size_t)cc * NTAP * 512 + (size_t)lane * 8;
        bf16x8 areg[9];
        #pragma unroll
        for (int tt = 0; tt < 9; ++tt) {
            int t = t0 + tt;
            int tc = (t < NTAP) ? t : (NTAP - 1);   // clamp (unused if t>=t1)
            areg[tt] = *(const bf16x8*)(wbase + (size_t)tc * 512);
        }
        #pragma unroll
        for (int tt = 0; tt < 9; ++tt) {
            if (tt < ntap) {                         // wave-uniform branch
                int t = t0 + tt;
                int kh = t / 7, kw = t - 7 * kh;
                bf16x8 b = *(const bf16x8*)&xs[kh][wg + 3 * kw][q * 8];
                acc = __builtin_amdgcn_mfma_f32_16x16x32_bf16(areg[tt], b, acc, 0, 0, 0);
            }
        }
    }

    // K-combine: groups 1..3 export fp32; group 0 sums and writes y3T bf16.
    if (g > 0) {
        cbuf[wt][g - 1][lane][0] = acc[0];
        cbuf[wt][g - 1][lane][1] = acc[1];
        cbuf[wt][g - 1][lane][2] = acc[2];
        cbuf[wt][g - 1][lane][3] = acc[3];
    }
    __syncthreads();
    if (g == 0) {
        #pragma unroll
        for (int p = 0; p < 3; ++p) {
            acc[0] += cbuf[wt][p][lane][0];
            acc[1] += cbuf[wt][p][lane][1];
            acc[2] += cbuf[wt][p][lane][2];
            acc[3] += cbuf[wt][p][lane][3];
        }
        // invalid cols (wl>=28) forced to finite zero
        u32 lo = wok ? pack2(acc[0], acc[1]) : 0u;
        u32 hi = wok ? pack2(acc[2], acc[3]) : 0u;
        *(u32*)&y3T[wl][q * 4]     = lo;
        *(u32*)&y3T[wl][q * 4 + 2] = hi;
    }
    __syncthreads();

    // Stage-2: wave (wt,g) -> o-tiles {2g, 2g+1} on its w-tile.
    bf16x8 bfrag = *(const bf16x8*)&y3T[wl][q * 8];
    #pragma unroll
    for (int i = 0; i < 2; ++i) {
        const int ot = 2 * g + i;
        bf16x8 afrag = *(const bf16x8*)(wsT + WS_WC + (size_t)(ot * 64 + lane) * 8);
        f32x4 c2 = {0.f, 0.f, 0.f, 0.f};
        c2 = __builtin_amdgcn_mfma_f32_16x16x32_bf16(afrag, bfrag, c2, 0, 0, 0);
        if (wok) {
            int o = ot * 16 + q * 4;
            float* po = out + ((size_t)(n * BC + o) * BH + h) * BW + wg;
            po[0]      = c2[0];
            po[HW]     = c2[1];
            po[2 * HW] = c2[2];
            po[3 * HW] = c2[3];
        }
    }
}

extern "C" void kernel_launch(void* const* d_in, const int* in_sizes, int n_in,
                              void* d_out, int out_size, void* d_ws, size_t ws_size,
                              hipStream_t stream)
{
    (void)in_sizes; (void)n_in; (void)out_size; (void)ws_size;
    const float* x  = (const float*)d_in[0];
    const float* w3 = (const float*)d_in[1];
    const float* w4 = (const float*)d_in[2];
    const float* w5 = (const float*)d_in[3];
    u16* ws = (u16*)d_ws;

    prep_all<<<2048 + 296, 256, 0, stream>>>(x, w3, w4, w5, ws);
    conv_mfma<<<BN * BH * 2, 512, 0, stream>>>(ws, (float*)d_out);
}

// Round 15
// 89.974 us; speedup vs baseline: 1.1424x; 1.0265x over previous
//
#include <hip/hip_runtime.h>

// Problem dims
#define BN 8
#define BC 128
#define BH 56
#define BW 56
#define HW 3136
#define NTAP 35
// u16 offsets inside ws:
#define WS_WC 71680                   // stage-2 Wc fragments [WS_WC, WS_WC+4096)
#define WS_XP (WS_WC + 4096)          // padded bf16 im2row x
#define XROW 2368                     // u16 per padded row = 74 cols * 32 ch
// LDS layout (bytes):
#define XS_OFF 0                      // xs[5][48][32] u16 = 15,360 B
#define Y3_OFF 15360                  // y3T[32][40] u16   =  2,560 B
#define WA_OFF 17920                  // wA[35][64][8] u16 = 35,840 B
#define SMEM_SZ 53760                 // 3 blocks/CU (cbuf aliases xs)

typedef unsigned short u16;
typedef unsigned int u32;
typedef __bf16 bf16x8 __attribute__((ext_vector_type(8)));
typedef float f32x4 __attribute__((ext_vector_type(4)));

__device__ __forceinline__ u16 f2b(float f) {
    unsigned u = __float_as_uint(f);
    return (u16)((u + 0x7FFFu + ((u >> 16) & 1u)) >> 16);  // RNE
}
__device__ __forceinline__ u32 pack2(float a, float b) {
    return (u32)f2b(a) | ((u32)f2b(b) << 16);
}
__device__ __forceinline__ void dma16(const void* g, void* l) {
    __builtin_amdgcn_global_load_lds(
        (const __attribute__((address_space(1))) u32*)g,
        (__attribute__((address_space(3))) u32*)l, 16, 0, 0);
}

// prep_all: blocks [0,2048) build padded bf16 im2row x; blocks [2048,2344)
// build frag-ordered w3 + folded Wc (= w5@w4, K zero-padded to 32).
__global__ __launch_bounds__(256) void prep_all(
    const float* __restrict__ x, const float* __restrict__ w3,
    const float* __restrict__ w4, const float* __restrict__ w5,
    u16* __restrict__ ws)
{
    const int b = blockIdx.x;
    const int tid = threadIdx.x;

    if (b >= 2048) {               // ---- weights part
        int i = (b - 2048) * 256 + tid;
        if (i < WS_WC) {
            int j = i & 7, lane = (i >> 3) & 63, r = i >> 9;   // r = cc*35+tap
            int tap = r % NTAP, cc = r / NTAP;
            int q = lane >> 4, lm = lane & 15;
            ws[i] = f2b(w3[(lm * BC + cc * 32 + q * 8 + j) * NTAP + tap]);
        } else if (i < WS_WC + 4096) {
            int i2 = i - WS_WC;
            int j = i2 & 7, lane = (i2 >> 3) & 63, ot = i2 >> 9;
            int q = lane >> 4, lm = lane & 15, o = ot * 16 + lm, k = q * 8 + j;
            float s = 0.f;
            if (k < 16)
                for (int c = 0; c < 16; ++c) s += w5[o * 16 + c] * w4[c * 16 + k];
            ws[i] = f2b(s);
        }
        return;
    }

    // ---- x part: xpad[n][cc][hp][col][c32] bf16, h/w zero-pad baked in.
    __shared__ float ls[32][57];
    const int hp = b & 63, cc = (b >> 6) & 3, n = b >> 8;
    u32* dst = (u32*)(ws + WS_XP + (size_t)((n * 4 + cc) * 64 + hp) * XROW);
    const int gr = hp - 4;

    if ((unsigned)gr >= BH) {
        for (int i = tid; i < XROW / 2; i += 256) dst[i] = 0u;
        return;
    }
    for (int i = tid; i < 32 * 14; i += 256) {
        int c = i / 14, w4i = i % 14;
        float4 v = *(const float4*)(x + ((size_t)(n * BC + cc * 32 + c) * BH + gr) * BW + 4 * w4i);
        ls[c][4 * w4i + 0] = v.x;
        ls[c][4 * w4i + 1] = v.y;
        ls[c][4 * w4i + 2] = v.z;
        ls[c][4 * w4i + 3] = v.w;
    }
    __syncthreads();
    for (int i = tid; i < 74 * 16; i += 256) {
        int col = i >> 4, cp = i & 15;
        int gw = col - 9;
        u32 v = 0u;
        if ((unsigned)gw < BW) v = pack2(ls[2 * cp][gw], ls[2 * cp + 1][gw]);
        dst[col * 16 + cp] = v;
    }
}

// Main: block = (n, h, w-half): 896 blocks x 512 threads (8 waves).
// Wave wv = (wt = wv>>2 w-tile, g = wv&3 tap-quarter 9/9/9/8). xs is the
// 48-col window for this half; wA in LDS (R14 showed global-A regresses).
// cbuf (K-combine) aliases xs after stage-1. MFMA full-exec; stores guarded.
__global__ __launch_bounds__(512, 6) void conv_mfma(
    const u16* __restrict__ wsT, float* __restrict__ out)
{
    __shared__ __align__(16) char smem[SMEM_SZ];
    u16* xs  = (u16*)(smem + XS_OFF);    // [5][48][32]
    u16* y3T = (u16*)(smem + Y3_OFF);    // [32][40]
    u16* wA  = (u16*)(smem + WA_OFF);    // [35][64][8]
    float* cbuf = (float*)(smem + XS_OFF); // [2][3][64][4] after stage-1

    const int n = blockIdx.x & 7;
    const int r0 = blockIdx.x >> 3;      // 0..111
    const int h = r0 >> 1, wh = r0 & 1;
    const int tid = threadIdx.x, lane = tid & 63, wv = tid >> 6;
    const int wt = wv >> 2, g = wv & 3;
    const int q = lane >> 4, lm = lane & 15;
    const int wl = wt * 16 + lm;         // local col [0,32); valid < 28
    const int wg = wh * 28 + wl;         // global col (guarded)
    const bool wok = (wl < 28);

    // one-time: zero y3T K-pad u16 cols 16..31 (rows 0..31)
    if (tid < 256) ((u32*)(y3T + (tid >> 3) * 40))[8 + (tid & 7)] = 0u;

    f32x4 acc = {0.f, 0.f, 0.f, 0.f};
    const int t0 = 9 * g;
    const int ntap = (g == 3) ? 8 : 9;   // wave-uniform

    for (int cc = 0; cc < 4; ++cc) {
        __syncthreads();   // prior cc's frag reads complete

        // xs: 5 rows x 3 KB window (48 cols; 2-col tail overrun is benign,
        // stays inside ws and is never read). 15 chunks of 1 KB DMA.
        const u16* xbase = wsT + WS_XP + (size_t)((n * 4 + cc) * 64 + h) * XROW
                         + wh * 28 * 32;
        for (int k = wv; k < 15; k += 8) {
            int r = k / 3, s = k - 3 * r;
            dma16(xbase + (size_t)(2 * r) * XROW + s * 512 + lane * 8,
                  smem + XS_OFF + r * 3072 + s * 1024 + lane * 16);
        }
        // wA: 35 chunks of 1 KB, frag-ordered straight copy.
        const u16* wbase = wsT + (size_t)cc * NTAP * 512;
        for (int k = wv; k < NTAP; k += 8)
            dma16(wbase + (size_t)k * 512 + lane * 8,
                  smem + WA_OFF + k * 1024 + lane * 16);

        __syncthreads();   // DMA drained + visible

        #pragma unroll
        for (int tt = 0; tt < 9; ++tt) {
            if (tt < ntap) {                       // wave-uniform
                int t = t0 + tt;
                int kh = t / 7, kw = t - 7 * kh;
                bf16x8 a = *(const bf16x8*)(wA + (size_t)(t * 64 + lane) * 8);
                bf16x8 b = *(const bf16x8*)(xs + ((kh * 48 + wl + 3 * kw) * 32 + q * 8));
                acc = __builtin_amdgcn_mfma_f32_16x16x32_bf16(a, b, acc, 0, 0, 0);
            }
        }
    }

    __syncthreads();       // ALL xs B-reads done before cbuf aliases xs
    if (g > 0) {
        float* cb = cbuf + ((wt * 3 + (g - 1)) * 64 + lane) * 4;
        cb[0] = acc[0]; cb[1] = acc[1]; cb[2] = acc[2]; cb[3] = acc[3];
    }
    __syncthreads();
    if (g == 0) {
        #pragma unroll
        for (int p = 0; p < 3; ++p) {
            const float* cb = cbuf + ((wt * 3 + p) * 64 + lane) * 4;
            acc[0] += cb[0]; acc[1] += cb[1]; acc[2] += cb[2]; acc[3] += cb[3];
        }
        // invalid cols (wl >= 28) forced to finite zero
        u32 lo = wok ? pack2(acc[0], acc[1]) : 0u;
        u32 hi = wok ? pack2(acc[2], acc[3]) : 0u;
        *(u32*)(y3T + wl * 40 + q * 4)     = lo;
        *(u32*)(y3T + wl * 40 + q * 4 + 2) = hi;
    }
    __syncthreads();

    // Stage-2: wave (wt,g) -> o-tiles {2g, 2g+1} on its w-tile.
    bf16x8 bfrag = *(const bf16x8*)(y3T + wl * 40 + q * 8);
    #pragma unroll
    for (int i = 0; i < 2; ++i) {
        const int ot = 2 * g + i;
        bf16x8 afrag = *(const bf16x8*)(wsT + WS_WC + (size_t)(ot * 64 + lane) * 8);
        f32x4 c2 = {0.f, 0.f, 0.f, 0.f};
        c2 = __builtin_amdgcn_mfma_f32_16x16x32_bf16(afrag, bfrag, c2, 0, 0, 0);
        if (wok) {
            int o = ot * 16 + q * 4;
            float* po = out + ((size_t)(n * BC + o) * BH + h) * BW + wg;
            po[0]      = c2[0];
            po[HW]     = c2[1];
            po[2 * HW] = c2[2];
            po[3 * HW] = c2[3];
        }
    }
}

extern "C" void kernel_launch(void* const* d_in, const int* in_sizes, int n_in,
                              void* d_out, int out_size, void* d_ws, size_t ws_size,
                              hipStream_t stream)
{
    (void)in_sizes; (void)n_in; (void)out_size; (void)ws_size;
    const float* x  = (const float*)d_in[0];
    const float* w3 = (const float*)d_in[1];
    const float* w4 = (const float*)d_in[2];
    const float* w5 = (const float*)d_in[3];
    u16* ws = (u16*)d_ws;

    prep_all<<<2048 + 296, 256, 0, stream>>>(x, w3, w4, w5, ws);
    conv_mfma<<<BN * BH * 2, 512, 0, stream>>>(ws, (float*)d_out);
}